// Round 1
// 2974.971 us; speedup vs baseline: 1.0062x; 1.0062x over previous
//
#include <hip/hip_runtime.h>

typedef unsigned short u16;
typedef __attribute__((ext_vector_type(4))) float f32x4;
typedef __attribute__((ext_vector_type(8))) __bf16 bf16x8;
typedef __attribute__((ext_vector_type(8))) u16 u16x8;
typedef __attribute__((ext_vector_type(4))) int i32x4;

#define MFMA(a, b, c) __builtin_amdgcn_mfma_f32_16x16x32_bf16(a, b, c, 0, 0, 0)

__device__ __forceinline__ u16 f2bf(float f) {
  union { float f; unsigned u; } v; v.f = f;
  unsigned r = v.u + 0x7FFFu + ((v.u >> 16) & 1u);
  return (u16)(r >> 16);
}
__device__ __forceinline__ float bf2f(u16 b) {
  union { unsigned u; float f; } v; v.u = ((unsigned)b) << 16; return v.f;
}
__device__ __forceinline__ float sigm(float x) { return 1.f / (1.f + __expf(-x)); }
__device__ __forceinline__ float tanh_(float x) {
  float e = __expf(-2.f * fabsf(x));
  float r = (1.f - e) / (1.f + e);
  return x < 0.f ? -r : r;
}

// ---------------------------------------------------------------------------
// Prelude: build fused weight Wcat[g][k] (1536 x 1024 bf16):
//   k <  512 -> Whh[g][k]   (h part)
//   k >= 512 -> Wih[g][k-512] (x part)
// ---------------------------------------------------------------------------
__global__ __launch_bounds__(256) void build_wcat(const float* __restrict__ Whh,
                                                  const float* __restrict__ Wih,
                                                  u16* __restrict__ Wcat) {
  int i = blockIdx.x * 256 + threadIdx.x;
  if (i >= 1536 * 1024 / 8) return;
  int e = i * 8;
  int g = e >> 10, k = e & 1023;
  const float* src = (k < 512) ? (Whh + g * 512 + k) : (Wih + g * 512 + (k - 512));
  u16x8 o;
#pragma unroll
  for (int j = 0; j < 8; ++j) o[j] = f2bf(src[j]);
  *(u16x8*)(Wcat + e) = o;
}

__global__ __launch_bounds__(256) void cvt_bf16(const float* __restrict__ src,
                                                u16* __restrict__ dst, int n8) {
  int i = blockIdx.x * 256 + threadIdx.x;
  if (i >= n8) return;
  int e = i * 8;
  u16x8 o;
#pragma unroll
  for (int j = 0; j < 8; ++j) o[j] = f2bf(src[e + j]);
  *(u16x8*)(dst + e) = o;
}

// ---------------------------------------------------------------------------
// Persistent GRU kernel. 256 blocks x 512 threads.
//   dir = blockIdx & 1 (0=fwd GRU, 1=bwd GRU), grp = blockIdx >> 1 (64 samples).
// Per step t: gates = [h | x_t](64x1024) @ Wcat^T(1024x1536), computed as
// 8 waves x 2 N-half-passes; 16x16x32 bf16 MFMA; h kept in LDS (bf16).
// Freeze mask: rows with t >= len keep h. 2 barriers per step.
//
// L2 policy: win (x stream, zero reuse) is loaded NON-TEMPORAL and hcat is
// stored NON-TEMPORAL so the 3MB/direction weight array stays L2-resident
// across steps/blocks (per-XCD working set = 3MB weights < 4MB L2).
// ---------------------------------------------------------------------------
#define LROW 520  // padded LDS row stride (bf16 elements) to break bank conflicts

__global__ __launch_bounds__(512, 2) void gru_persistent(
    const float* __restrict__ win, const int* __restrict__ wlen,
    const u16* __restrict__ Wcat_f, const u16* __restrict__ Wcat_b,
    const float* __restrict__ bih_f, const float* __restrict__ bhh_f,
    const float* __restrict__ bih_b, const float* __restrict__ bhh_b,
    u16* __restrict__ hcat) {
  extern __shared__ char smem[];
  u16* h_s = (u16*)smem;                          // [64][LROW]
  u16* x_s = (u16*)(smem + 64 * LROW * 2);        // [64][LROW]
  int* len_s = (int*)(smem + 2 * 64 * LROW * 2);  // [64]
  int* bmax_s = len_s + 64;

  const int dir = blockIdx.x & 1;
  const int grp = blockIdx.x >> 1;
  const int s0 = grp * 64;
  const u16* W = dir ? Wcat_b : Wcat_f;
  const float* bih = dir ? bih_b : bih_f;
  const float* bhh = dir ? bhh_b : bhh_f;

  const int tid = threadIdx.x;
  const int wave = tid >> 6;
  const int lane = tid & 63;
  const int ln = lane & 15;
  const int ks = lane >> 4;  // 0..3

  // ---- init: zero h, compute lengths + block max length ----
  if (tid == 0) *bmax_s = 0;
  for (int i = tid; i < 64 * LROW / 8; i += 512) ((u16x8*)h_s)[i] = (u16x8)0;
  __syncthreads();
  if (tid < 64) {
    int wl = wlen[s0 + tid];
    int len = dir ? (wl / 2 + 1) : ((wl - 1) / 2 + 1);
    len_s[tid] = len;
    atomicMax(bmax_s, len);
  }
  __syncthreads();
  const int bmax = *bmax_s;

  // ---- bias preload: fixed columns per lane across all steps ----
  float b_r[2][2], b_z[2][2], b_hn[2][2], b_xn[2][2];
#pragma unroll
  for (int p = 0; p < 2; ++p)
#pragma unroll
    for (int c = 0; c < 2; ++c) {
      int d = (p * 16 + wave * 2 + c) * 16 + ln;
      b_r[p][c] = bih[d] + bhh[d];
      b_z[p][c] = bih[512 + d] + bhh[512 + d];
      b_xn[p][c] = bih[1024 + d];
      b_hn[p][c] = bhh[1024 + d];
    }

  // ---- x staging thread mapping: 8 threads per sample row ----
  const int xrow = tid >> 3;  // 0..63 sample-in-group
  const int xcol = tid & 7;
  const int mylen = len_s[xrow];
  // window row index: fwd: (8-len)+t ; bwd: (6+len)-t   (always in [0,14])
  const long xbase = (long)(s0 + xrow) * 15 + (dir ? (6 + mylen) : (8 - mylen));

  f32x4 accr[2][4], accz[2][4], acchn[2][4], accxn[2][4];
  u16 holdv[2][4][4];

  for (int t = 0; t < bmax; ++t) {
    // ---- stage x_t into LDS (f32 -> bf16), NON-TEMPORAL reads ----
    {
      long rowidx = dir ? (xbase - t) : (xbase + t);
      const float* src = win + rowidx * 512;
      u16* dst = x_s + xrow * LROW;
#pragma unroll
      for (int i = 0; i < 8; ++i) {
        int off = xcol * 8 + i * 64;
        f32x4 v0 = __builtin_nontemporal_load((const f32x4*)(src + off));
        f32x4 v1 = __builtin_nontemporal_load((const f32x4*)(src + off + 4));
        u16x8 o;
        o[0] = f2bf(v0[0]); o[1] = f2bf(v0[1]); o[2] = f2bf(v0[2]); o[3] = f2bf(v0[3]);
        o[4] = f2bf(v1[0]); o[5] = f2bf(v1[1]); o[6] = f2bf(v1[2]); o[7] = f2bf(v1[3]);
        *(u16x8*)(dst + off) = o;
      }
    }
    __syncthreads();  // BAR_A: x_t staged, h from previous step visible

    // ---- two N-half passes over this wave's gate-column chunks ----
#pragma unroll
    for (int p = 0; p < 2; ++p) {
      const int c0 = p * 16 + wave * 2;  // this wave's first 16-col chunk
#pragma unroll
      for (int c = 0; c < 2; ++c)
#pragma unroll
        for (int mt = 0; mt < 4; ++mt)
#pragma unroll
          for (int j = 0; j < 4; ++j) {
            accr[c][mt][j] = 0.f; accz[c][mt][j] = 0.f;
            acchn[c][mt][j] = 0.f; accxn[c][mt][j] = 0.f;
          }

      // K-loop, h half (k in [0,512)): accumulate r, z, hn
#pragma unroll
      for (int kk = 0; kk < 16; ++kk) {
        bf16x8 a[4];
        const int krel = kk * 32 + ks * 8;
#pragma unroll
        for (int mt = 0; mt < 4; ++mt)
          a[mt] = *(const bf16x8*)(h_s + (mt * 16 + ln) * LROW + krel);
#pragma unroll
        for (int c = 0; c < 2; ++c) {
          const u16* wb = W + (size_t)((c0 + c) * 16 + ln) * 1024 + kk * 32 + ks * 8;
          bf16x8 br = *(const bf16x8*)(wb);
          bf16x8 bz = *(const bf16x8*)(wb + 512 * 1024);
          bf16x8 bn = *(const bf16x8*)(wb + 1024 * 1024);
#pragma unroll
          for (int mt = 0; mt < 4; ++mt) {
            accr[c][mt] = MFMA(a[mt], br, accr[c][mt]);
            accz[c][mt] = MFMA(a[mt], bz, accz[c][mt]);
            acchn[c][mt] = MFMA(a[mt], bn, acchn[c][mt]);
          }
        }
      }
      // K-loop, x half (k in [512,1024)): accumulate r, z, xn
#pragma unroll
      for (int kk = 0; kk < 16; ++kk) {
        bf16x8 a[4];
        const int krel = kk * 32 + ks * 8;
#pragma unroll
        for (int mt = 0; mt < 4; ++mt)
          a[mt] = *(const bf16x8*)(x_s + (mt * 16 + ln) * LROW + krel);
#pragma unroll
        for (int c = 0; c < 2; ++c) {
          const u16* wb = W + (size_t)((c0 + c) * 16 + ln) * 1024 + 512 + kk * 32 + ks * 8;
          bf16x8 br = *(const bf16x8*)(wb);
          bf16x8 bz = *(const bf16x8*)(wb + 512 * 1024);
          bf16x8 bn = *(const bf16x8*)(wb + 1024 * 1024);
#pragma unroll
          for (int mt = 0; mt < 4; ++mt) {
            accr[c][mt] = MFMA(a[mt], br, accr[c][mt]);
            accz[c][mt] = MFMA(a[mt], bz, accz[c][mt]);
            accxn[c][mt] = MFMA(a[mt], bn, accxn[c][mt]);
          }
        }
      }

      if (p == 0) {
        // pass-0 epilogue: compute h_new, HOLD in registers (h_s still being
        // read by other waves' pass-1 K-loops)
#pragma unroll
        for (int c = 0; c < 2; ++c) {
          const int d = (c0 + c) * 16 + ln;
#pragma unroll
          for (int mt = 0; mt < 4; ++mt)
#pragma unroll
            for (int j = 0; j < 4; ++j) {
              int row = mt * 16 + ks * 4 + j;
              float rr = sigm(accr[c][mt][j] + b_r[0][c]);
              float zz = sigm(accz[c][mt][j] + b_z[0][c]);
              float nn = tanh_(accxn[c][mt][j] + b_xn[0][c] +
                               rr * (acchn[c][mt][j] + b_hn[0][c]));
              float hold = bf2f(h_s[row * LROW + d]);
              float hnew = (t < len_s[row]) ? ((1.f - zz) * nn + zz * hold) : hold;
              holdv[c][mt][j] = f2bf(hnew);
            }
        }
      } else {
        __syncthreads();  // BAR_B: all reads of h_s for this step are done
        // write held pass-0 h_new (cols [0,256))
#pragma unroll
        for (int c = 0; c < 2; ++c) {
          const int d = (wave * 2 + c) * 16 + ln;
#pragma unroll
          for (int mt = 0; mt < 4; ++mt)
#pragma unroll
            for (int j = 0; j < 4; ++j) {
              int row = mt * 16 + ks * 4 + j;
              h_s[row * LROW + d] = holdv[c][mt][j];
            }
        }
        // pass-1 epilogue: compute and write directly (cols [256,512))
#pragma unroll
        for (int c = 0; c < 2; ++c) {
          const int d = (c0 + c) * 16 + ln;
#pragma unroll
          for (int mt = 0; mt < 4; ++mt)
#pragma unroll
            for (int j = 0; j < 4; ++j) {
              int row = mt * 16 + ks * 4 + j;
              float rr = sigm(accr[c][mt][j] + b_r[1][c]);
              float zz = sigm(accz[c][mt][j] + b_z[1][c]);
              float nn = tanh_(accxn[c][mt][j] + b_xn[1][c] +
                               rr * (acchn[c][mt][j] + b_hn[1][c]));
              float hold = bf2f(h_s[row * LROW + d]);
              float hnew = (t < len_s[row]) ? ((1.f - zz) * nn + zz * hold) : hold;
              h_s[row * LROW + d] = f2bf(hnew);
            }
        }
      }
    }  // passes
  }    // t

  __syncthreads();  // final h writes visible
  // ---- write final h to hcat[s][dir*512 + k], NON-TEMPORAL ----
#pragma unroll
  for (int i = 0; i < 8; ++i) {
    int off = xcol * 8 + i * 64;
    u16x8 v = *(const u16x8*)(h_s + xrow * LROW + off);
    __builtin_nontemporal_store(
        v, (u16x8*)(hcat + (size_t)(s0 + xrow) * 1024 + dir * 512 + off));
  }
}

// ---------------------------------------------------------------------------
// MLP GEMM: out[M,N] = act(A[M,K] @ Bw[N,K]^T + bias)
// mode=1: relu + bf16 out ; mode=0: f32 out. 128x128 tile, 256 threads.
// ---------------------------------------------------------------------------
__global__ __launch_bounds__(256) void mlp_gemm(const u16* __restrict__ A,
                                                const u16* __restrict__ Bw,
                                                const float* __restrict__ bias,
                                                void* __restrict__ out, int M,
                                                int N, int K, int mode) {
  __shared__ u16 As[128 * 64], Bs[128 * 64];
  const int tid = threadIdx.x;
  const int wave = tid >> 6, lane = tid & 63;
  const int ln = lane & 15, ks = lane >> 4;
  const int wm = wave & 1, wn = wave >> 1;
  const int m0 = blockIdx.x * 128, n0 = blockIdx.y * 128;
  f32x4 acc[4][4];
#pragma unroll
  for (int mt = 0; mt < 4; ++mt)
#pragma unroll
    for (int nt = 0; nt < 4; ++nt)
#pragma unroll
      for (int j = 0; j < 4; ++j) acc[mt][nt][j] = 0.f;

  const int r = tid >> 1, hh = tid & 1;
  for (int k0 = 0; k0 < K; k0 += 64) {
    const i32x4* sa = (const i32x4*)(A + (size_t)(m0 + r) * K + k0 + hh * 32);
    const i32x4* sb = (const i32x4*)(Bw + (size_t)(n0 + r) * K + k0 + hh * 32);
    i32x4* da = (i32x4*)(As + r * 64 + hh * 32);
    i32x4* db = (i32x4*)(Bs + r * 64 + hh * 32);
#pragma unroll
    for (int i = 0; i < 4; ++i) da[i] = sa[i];
#pragma unroll
    for (int i = 0; i < 4; ++i) db[i] = sb[i];
    __syncthreads();
#pragma unroll
    for (int kk = 0; kk < 2; ++kk) {
      bf16x8 af[4], bfm[4];
#pragma unroll
      for (int mt = 0; mt < 4; ++mt)
        af[mt] = *(const bf16x8*)(As + (wm * 64 + mt * 16 + ln) * 64 + kk * 32 + ks * 8);
#pragma unroll
      for (int nt = 0; nt < 4; ++nt)
        bfm[nt] = *(const bf16x8*)(Bs + (wn * 64 + nt * 16 + ln) * 64 + kk * 32 + ks * 8);
#pragma unroll
      for (int mt = 0; mt < 4; ++mt)
#pragma unroll
        for (int nt = 0; nt < 4; ++nt) acc[mt][nt] = MFMA(af[mt], bfm[nt], acc[mt][nt]);
    }
    __syncthreads();
  }

#pragma unroll
  for (int nt = 0; nt < 4; ++nt) {
    int col = n0 + wn * 64 + nt * 16 + ln;
    float bv = bias[col];
#pragma unroll
    for (int mt = 0; mt < 4; ++mt)
#pragma unroll
      for (int j = 0; j < 4; ++j) {
        int row = m0 + wm * 64 + mt * 16 + ks * 4 + j;
        float v = acc[mt][nt][j] + bv;
        if (mode) {
          v = fmaxf(v, 0.f);
          ((u16*)out)[(size_t)row * N + col] = f2bf(v);
        } else {
          ((float*)out)[(size_t)row * N + col] = v;
        }
      }
  }
}

// ---------------------------------------------------------------------------
extern "C" void kernel_launch(void* const* d_in, const int* in_sizes, int n_in,
                              void* d_out, int out_size, void* d_ws, size_t ws_size,
                              hipStream_t stream) {
  (void)in_sizes; (void)n_in; (void)out_size; (void)ws_size;
  const float* win = (const float*)d_in[0];
  const int* wlen = (const int*)d_in[1];
  const float* Wih_f = (const float*)d_in[2];
  const float* Whh_f = (const float*)d_in[3];
  const float* bih_f = (const float*)d_in[4];
  const float* bhh_f = (const float*)d_in[5];
  const float* Wih_b = (const float*)d_in[6];
  const float* Whh_b = (const float*)d_in[7];
  const float* bih_b = (const float*)d_in[8];
  const float* bhh_b = (const float*)d_in[9];
  const float* W1 = (const float*)d_in[10];
  const float* b1 = (const float*)d_in[11];
  const float* W2 = (const float*)d_in[12];
  const float* b2 = (const float*)d_in[13];

  char* ws = (char*)d_ws;
  u16* Wcat_f = (u16*)ws;  ws += 3145728;
  u16* Wcat_b = (u16*)ws;  ws += 3145728;
  u16* W1b = (u16*)ws;     ws += 1048576;
  u16* W2b = (u16*)ws;     ws += 524288;
  u16* hcat = (u16*)ws;    ws += 16777216;
  u16* hidden = (u16*)ws;  ws += 8388608;

  build_wcat<<<768, 256, 0, stream>>>(Whh_f, Wih_f, Wcat_f);
  build_wcat<<<768, 256, 0, stream>>>(Whh_b, Wih_b, Wcat_b);
  cvt_bf16<<<256, 256, 0, stream>>>(W1, W1b, 65536);
  cvt_bf16<<<128, 256, 0, stream>>>(W2, W2b, 32768);

  const int SMEM = 2 * 64 * LROW * 2 + 64 * 4 + 16;  // h + x + lens + bmax
  (void)hipFuncSetAttribute((const void*)gru_persistent,
                            hipFuncAttributeMaxDynamicSharedMemorySize, SMEM);
  gru_persistent<<<256, 512, SMEM, stream>>>(win, wlen, Wcat_f, Wcat_b, bih_f,
                                             bhh_f, bih_b, bhh_b, hcat);

  mlp_gemm<<<dim3(64, 4), 256, 0, stream>>>(hcat, W1b, b1, hidden, 8192, 512, 1024, 1);
  mlp_gemm<<<dim3(64, 4), 256, 0, stream>>>(hidden, W2b, b2, d_out, 8192, 512, 512, 0);
}